// Round 7
// baseline (2671.580 us; speedup 1.0000x reference)
//
#include <hip/hip_runtime.h>
#include <cstdint>
#include <cmath>

// LSTM: B=64, T=2048, H=128, gates=4H=512. f32 throughout.
//
// Round 7 = Round 6 design with the preprocessor bug fixed (W##0.x pasted
// 'qa' against pp-number '0.x'; now four explicit float4 args per FMA_Q).
// R5 cost model (per step per CU, 16 waves): 512 FMA floor + 512 trans
// + ~700 LDS (64 ds_read_b128) + ~350 VALU misc + barrier ~= 2100 cy.
//   rec: 512 threads = 8 waves; 8-lane group owns TWO units (g, g+64);
//        128 pinned weights/thread; same h chunk feeds both units' dots.
//        -> trans 512->256 cy, LDS 64->32 insts, VALU issue ~790 cy.
//   xproj: 2-row register blocking (rows j, j+256 share an output float4),
//        x read directly from global (uniform addr -> broadcast), no LDS.

#define HID 128
#define G4  512
#define BB  64
#define TT  2048

#define PIN4(v) asm volatile("" : "+v"((v).x), "+v"((v).y), "+v"((v).z), "+v"((v).w))

template<int CTRL>
__device__ __forceinline__ float dpp_mov(float v) {
    return __int_as_float(__builtin_amdgcn_update_dpp(
        0, __float_as_int(v), CTRL, 0xF, 0xF, false));
}
// 8-lane butterfly sum (validated R5): xor1=0xB1, xor2=0x4E, xor7=0x141.
#define BF8(p) { p += dpp_mov<0xB1>(p); p += dpp_mov<0x4E>(p); p += dpp_mov<0x141>(p); }

// ---------------- xproj: 256 threads, 16-row tile, 2 gate rows per thread
#define DECL_W16P(pre, p) \
    float4 pre##0=(p)[0],  pre##1=(p)[1],  pre##2=(p)[2],  pre##3=(p)[3],  \
           pre##4=(p)[4],  pre##5=(p)[5],  pre##6=(p)[6],  pre##7=(p)[7],  \
           pre##8=(p)[8],  pre##9=(p)[9],  pre##10=(p)[10],pre##11=(p)[11],\
           pre##12=(p)[12],pre##13=(p)[13],pre##14=(p)[14],pre##15=(p)[15];
#define LOAD_W16P(pre, p) \
    pre##0=(p)[0];  pre##1=(p)[1];  pre##2=(p)[2];  pre##3=(p)[3];  \
    pre##4=(p)[4];  pre##5=(p)[5];  pre##6=(p)[6];  pre##7=(p)[7];  \
    pre##8=(p)[8];  pre##9=(p)[9];  pre##10=(p)[10];pre##11=(p)[11];\
    pre##12=(p)[12];pre##13=(p)[13];pre##14=(p)[14];pre##15=(p)[15];
#define PIN_W16P(pre) \
    PIN4(pre##0);  PIN4(pre##1);  PIN4(pre##2);  PIN4(pre##3);  \
    PIN4(pre##4);  PIN4(pre##5);  PIN4(pre##6);  PIN4(pre##7);  \
    PIN4(pre##8);  PIN4(pre##9);  PIN4(pre##10); PIN4(pre##11); \
    PIN4(pre##12); PIN4(pre##13); PIN4(pre##14); PIN4(pre##15);

#define XFMA(i) { const float4 v = xp[i]; \
    a0 = fmaf(ua##i.x, v.x, a0); a1 = fmaf(ua##i.y, v.y, a1); \
    a2 = fmaf(ua##i.z, v.z, a2); a3 = fmaf(ua##i.w, v.w, a3); \
    b0 = fmaf(ub##i.x, v.x, b0); b1 = fmaf(ub##i.y, v.y, b1); \
    b2 = fmaf(ub##i.z, v.z, b2); b3 = fmaf(ub##i.w, v.w, b3); }
#define XDOT64 \
    XFMA(0)  XFMA(1)  XFMA(2)  XFMA(3)  XFMA(4)  XFMA(5)  XFMA(6)  XFMA(7) \
    XFMA(8)  XFMA(9)  XFMA(10) XFMA(11) XFMA(12) XFMA(13) XFMA(14) XFMA(15)

__global__ __launch_bounds__(256)
__attribute__((amdgpu_waves_per_eu(2, 2)))
void xproj_kernel(const float* __restrict__ x, const float* __restrict__ W_ih,
                  const float* __restrict__ b_ih, const float* __restrict__ b_hh,
                  float* __restrict__ xg, int t0, int Tc) {
    const int j    = threadIdx.x;                  // gate rows j and j+256
    const int row0 = blockIdx.x * 16;              // Tc % 16 == 0 -> tile in one b
    const int b    = row0 / Tc;
    const int tc0  = row0 % Tc;

    const float* xrow = x + ((size_t)b * TT + (size_t)t0 + tc0) * HID;
    const float bias0 = b_ih[j]       + b_hh[j];
    const float bias1 = b_ih[j + 256] + b_hh[j + 256];

    const float4* wrA = reinterpret_cast<const float4*>(W_ih + (size_t)j * HID);
    const float4* wrB = reinterpret_cast<const float4*>(W_ih + (size_t)(j + 256) * HID);
    DECL_W16P(ua, wrA)                             // rows' k = 0..63
    DECL_W16P(ub, wrB)
    PIN_W16P(ua)
    PIN_W16P(ub)

    float acc[16], accB[16];
    #pragma unroll
    for (int r = 0; r < 16; ++r) {                 // pass 0: k = 0..63
        const float4* xp = reinterpret_cast<const float4*>(xrow + r * HID);
        float a0 = 0.f, a1 = 0.f, a2 = 0.f, a3 = 0.f;
        float b0 = 0.f, b1 = 0.f, b2 = 0.f, b3 = 0.f;
        XDOT64
        acc[r]  = bias0 + (a0 + a1) + (a2 + a3);
        accB[r] = bias1 + (b0 + b1) + (b2 + b3);
    }
    LOAD_W16P(ua, wrA + 16)                        // k = 64..127
    LOAD_W16P(ub, wrB + 16)
    PIN_W16P(ua)
    PIN_W16P(ub)
    #pragma unroll
    for (int r = 0; r < 16; ++r) {                 // pass 1
        const float4* xp = reinterpret_cast<const float4*>(xrow + r * HID) + 16;
        float a0 = 0.f, a1 = 0.f, a2 = 0.f, a3 = 0.f;
        float b0 = 0.f, b1 = 0.f, b2 = 0.f, b3 = 0.f;
        XDOT64
        acc[r]  += (a0 + a1) + (a2 + a3);
        accB[r] += (b0 + b1) + (b2 + b3);
    }

    // gate-interleaved: pos = hid*4 + gate. row j -> gate j>>7; row j+256 -> +2.
    float* dst = xg + ((size_t)b * Tc + tc0) * G4 + ((j & 127) << 2) + (j >> 7);
    #pragma unroll
    for (int r = 0; r < 16; ++r) {
        dst[(size_t)r * G4]     = acc[r];
        dst[(size_t)r * G4 + 2] = accB[r];
    }
}

// ---------------- recurrence: 512 threads, 8-lane group owns units (g, g+64)
#define DECL_Q(P, ptr) float4 P##0=(ptr)[0], P##1=(ptr)[1], P##2=(ptr)[2], P##3=(ptr)[3];
#define PIN_Q(P) PIN4(P##0); PIN4(P##1); PIN4(P##2); PIN4(P##3);

// four explicit float4 args -> no digit token-pasting (R6 bug fix)
#define FMA_Q(P, A, B, C, D) \
  P = fmaf((A).x, hc0.x, P); P = fmaf((A).y, hc0.y, P); P = fmaf((A).z, hc0.z, P); P = fmaf((A).w, hc0.w, P); \
  P = fmaf((B).x, hc1.x, P); P = fmaf((B).y, hc1.y, P); P = fmaf((B).z, hc1.z, P); P = fmaf((B).w, hc1.w, P); \
  P = fmaf((C).x, hc2.x, P); P = fmaf((C).y, hc2.y, P); P = fmaf((C).z, hc2.z, P); P = fmaf((C).w, hc2.w, P); \
  P = fmaf((D).x, hc3.x, P); P = fmaf((D).y, hc3.y, P); P = fmaf((D).z, hc3.z, P); P = fmaf((D).w, hc3.w, P);

__global__ __launch_bounds__(512)
__attribute__((amdgpu_waves_per_eu(2, 2)))
void lstm_rec_kernel(const float* __restrict__ xg, const float* __restrict__ h0,
                     const float* __restrict__ c0, const float* __restrict__ W_hh,
                     float* __restrict__ out, float* __restrict__ hstate,
                     float* __restrict__ cstate, int t0, int Tc) {
    // padded double buffer (R5 layout): value k at 20*(k>>4)+(k&15); chunk l
    // base = 80l B -> banks {0,20,8,28,16,4,24,12}: conflict-free reads.
    __shared__ __align__(16) float h_lds[2][160];
    const int t   = threadIdx.x;
    const int g   = t >> 3;                        // group 0..63
    const int l   = t & 7;                         // lane in group = k-chunk
    const int u   = l >> 2;                        // unit half
    const int sel = l & 3;                         // gate this lane owns
    const int b   = blockIdx.x;
    const int jj  = g + (u << 6);                  // this lane's unit (g or g+64)

    // 8 weight rows x 16-float chunk: units {g, g+64} x gates {i,f,g,o}
    const float* wl = W_hh + 16 * l;
    const float4* pa = reinterpret_cast<const float4*>(wl + (size_t)(  0 + g     ) * HID);
    const float4* pb = reinterpret_cast<const float4*>(wl + (size_t)(128 + g     ) * HID);
    const float4* pc = reinterpret_cast<const float4*>(wl + (size_t)(256 + g     ) * HID);
    const float4* pd = reinterpret_cast<const float4*>(wl + (size_t)(384 + g     ) * HID);
    const float4* pe = reinterpret_cast<const float4*>(wl + (size_t)(  0 + g + 64) * HID);
    const float4* pf = reinterpret_cast<const float4*>(wl + (size_t)(128 + g + 64) * HID);
    const float4* pg = reinterpret_cast<const float4*>(wl + (size_t)(256 + g + 64) * HID);
    const float4* ph = reinterpret_cast<const float4*>(wl + (size_t)(384 + g + 64) * HID);
    DECL_Q(qa, pa) DECL_Q(qb, pb) DECL_Q(qc, pc) DECL_Q(qd, pd)
    DECL_Q(qe, pe) DECL_Q(qf, pf) DECL_Q(qg, pg) DECL_Q(qh, ph)
    PIN_Q(qa) PIN_Q(qb) PIN_Q(qc) PIN_Q(qd)
    PIN_Q(qe) PIN_Q(qf) PIN_Q(qg) PIN_Q(qh)

    float c = (t0 == 0) ? c0[b * HID + jj] : cstate[b * HID + jj];  // x4 in quad
    if (t < HID) {
        const int pi = 20 * (t >> 4) + (t & 15);
        h_lds[0][pi] = (t0 == 0) ? h0[b * HID + t] : hstate[b * HID + t];
    }
    __syncthreads();

    float4 hc0 = *reinterpret_cast<const float4*>(&h_lds[0][20 * l + 0]);
    float4 hc1 = *reinterpret_cast<const float4*>(&h_lds[0][20 * l + 4]);
    float4 hc2 = *reinterpret_cast<const float4*>(&h_lds[0][20 * l + 8]);
    float4 hc3 = *reinterpret_cast<const float4*>(&h_lds[0][20 * l + 12]);

    const float* xq   = xg  + (size_t)b * Tc * G4 + 4 * jj;  // gate-interleaved
    float*       outp = out + ((size_t)b * TT + t0) * HID + jj;
    float4 xn = *reinterpret_cast<const float4*>(xq);

    for (int tc = 0; tc < Tc; ++tc) {
        float4 xnn = xn;
        if (tc + 1 < Tc)                            // uniform branch
            xnn = *reinterpret_cast<const float4*>(xq + (size_t)(tc + 1) * G4);

        float p0 = 0.f, p1 = 0.f, p2 = 0.f, p3 = 0.f;
        float p4 = 0.f, p5 = 0.f, p6 = 0.f, p7 = 0.f;
        FMA_Q(p0, qa0, qa1, qa2, qa3)
        FMA_Q(p1, qb0, qb1, qb2, qb3)
        FMA_Q(p2, qc0, qc1, qc2, qc3)
        FMA_Q(p3, qd0, qd1, qd2, qd3)
        FMA_Q(p4, qe0, qe1, qe2, qe3)
        FMA_Q(p5, qf0, qf1, qf2, qf3)
        FMA_Q(p6, qg0, qg1, qg2, qg3)
        FMA_Q(p7, qh0, qh1, qh2, qh3)
        BF8(p0) BF8(p1) BF8(p2) BF8(p3) BF8(p4) BF8(p5) BF8(p6) BF8(p7)

        // lane l owns (unit u, gate sel): pick its summed pre-activation + xg
        float xv = u == 0
            ? (sel == 0 ? p0 : sel == 1 ? p1 : sel == 2 ? p2 : p3)
            : (sel == 0 ? p4 : sel == 1 ? p5 : sel == 2 ? p6 : p7);
        xv += (sel == 0 ? xn.x : sel == 1 ? xn.y : sel == 2 ? xn.z : xn.w);

        const float mm = (sel == 2) ? 2.f : 1.f;    // gate g: tanh = 2*sig(2x)-1
        const float e  = __expf(-xv * mm);
        float r  = 1.f / (1.f + e);
        r = (sel == 2) ? 2.f * r - 1.f : r;

        const float vi = dpp_mov<0x00>(r);          // quad bcast: i,f,g,o
        const float vf = dpp_mov<0x55>(r);
        const float vg = dpp_mov<0xAA>(r);
        const float vo = dpp_mov<0xFF>(r);
        c = fmaf(vf, c, vi * vg);
        const float th = 2.f / (1.f + __expf(-2.f * c)) - 1.f;  // tanh(c)
        const float h  = vo * th;

        const int nb = (tc + 1) & 1;
        if (sel == 0) {
            h_lds[nb][20 * (jj >> 4) + (jj & 15)] = h;
            outp[(size_t)tc * HID] = h;
        }
        __syncthreads();                            // ONE barrier per step
        hc0 = *reinterpret_cast<const float4*>(&h_lds[nb][20 * l + 0]);
        hc1 = *reinterpret_cast<const float4*>(&h_lds[nb][20 * l + 4]);
        hc2 = *reinterpret_cast<const float4*>(&h_lds[nb][20 * l + 8]);
        hc3 = *reinterpret_cast<const float4*>(&h_lds[nb][20 * l + 12]);
        xn = xnn;
    }
    if (sel == 0) cstate[b * HID + jj] = c;
    if (t < HID) {
        const int pi = 20 * (t >> 4) + (t & 15);
        hstate[b * HID + t] = h_lds[Tc & 1][pi];
    }
}

extern "C" void kernel_launch(void* const* d_in, const int* in_sizes, int n_in,
                              void* d_out, int out_size, void* d_ws, size_t ws_size,
                              hipStream_t stream) {
    const float* x    = (const float*)d_in[0];
    const float* h0   = (const float*)d_in[1];
    const float* c0   = (const float*)d_in[2];
    const float* W_ih = (const float*)d_in[3];
    const float* W_hh = (const float*)d_in[4];
    const float* b_ih = (const float*)d_in[5];
    const float* b_hh = (const float*)d_in[6];
    float* out = (float*)d_out;

    char*  ws     = (char*)d_ws;
    float* hstate = (float*)ws;                    // 32 KB
    float* cstate = (float*)(ws + 32768);          // 32 KB
    float* xg     = (float*)(ws + 65536);

    const size_t per_t = (size_t)BB * G4 * sizeof(float);   // 128 KB per timestep
    size_t avail = ws_size > 65536 ? ws_size - 65536 : 0;
    long long tc_ll = (long long)(avail / per_t);
    int Tc = tc_ll > TT ? TT : (int)tc_ll;
    Tc = (Tc / 64) * 64;
    if (Tc < 64) Tc = 64;

    for (int t0 = 0; t0 < TT; t0 += Tc) {
        const int Tcur = (TT - t0 < Tc) ? (TT - t0) : Tc;
        // xproj: 16 rows per block, 256 threads -> 4*Tcur blocks
        xproj_kernel<<<dim3(4 * Tcur), dim3(256), 0, stream>>>(x, W_ih, b_ih, b_hh,
                                                               xg, t0, Tcur);
        lstm_rec_kernel<<<dim3(BB), dim3(512), 0, stream>>>(xg, h0, c0, W_hh, out,
                                                            hstate, cstate, t0, Tcur);
    }
}

// Round 8
// 2128.419 us; speedup vs baseline: 1.2552x; 1.2552x over previous
//
#include <hip/hip_runtime.h>
#include <cstdint>
#include <cmath>

// LSTM: B=64, T=2048, H=128, gates=4H=512. f32 throughout.
//
// Round 8:
//  - xproj reverted to R5 LDS-staged structure (R7's uniform-global-read xproj
//    regressed 510->~1100 us: 512 serial broadcast loads, 2 waves/EU).
//  - rec is VALU-ISSUE-bound (VALUBusy ~99% on its 64 CUs) at ~450 insts/step
//    vs ~210 in source: VGPR_Count=88 says weights live in AGPRs with per-use
//    copies. Fix: (a) v_pk_fma_f32 via ext_vector float2 + elementwise_fma
//    (halves dot issue), (b) re-pin weights INSIDE the step loop so an AGPR
//    home costs 128 copies/iter -> allocator must use true VGPRs.

#define HID 128
#define G4  512
#define BB  64
#define TT  2048

typedef float v2f __attribute__((ext_vector_type(2)));
typedef float v4f __attribute__((ext_vector_type(4)));

#define PIN2(v) asm volatile("" : "+v"(v))
#define FMA2(A, B, C) __builtin_elementwise_fma((A), (B), (C))

template<int CTRL>
__device__ __forceinline__ float dpp_mov(float v) {
    return __int_as_float(__builtin_amdgcn_update_dpp(
        0, __float_as_int(v), CTRL, 0xF, 0xF, false));
}
// 8-lane butterfly sum (validated R5/R7): xor1=0xB1, xor2=0x4E, mirror8=0x141.
#define BF8(p) { p += dpp_mov<0xB1>(p); p += dpp_mov<0x4E>(p); p += dpp_mov<0x141>(p); }

// ---------------- xproj: R5 structure, pk-fma inner loop
__global__ __launch_bounds__(512)
__attribute__((amdgpu_waves_per_eu(4, 4)))
void xproj_kernel(const float* __restrict__ x, const float* __restrict__ W_ih,
                  const float* __restrict__ b_ih, const float* __restrict__ b_hh,
                  float* __restrict__ xg, int t0, int Tc) {
    __shared__ __align__(16) v4f xs4[16 * 32];     // 16 rows x 128 f32 = 8 KB
    const int j    = threadIdx.x;                  // gate row 0..511
    const int row0 = blockIdx.x * 16;              // Tc % 16 == 0 -> tile in one b
    const int b    = row0 / Tc;
    const int tc0  = row0 % Tc;

    const float* xsrc = x + ((size_t)b * TT + (size_t)t0 + tc0) * HID;
    xs4[j] = reinterpret_cast<const v4f*>(xsrc)[j];   // 512 v4f = whole tile

    const float bias = b_ih[j] + b_hh[j];
    const v4f* wr4 = reinterpret_cast<const v4f*>(W_ih + (size_t)j * HID);

    v2f wv[32];
    #pragma unroll
    for (int k = 0; k < 16; ++k) {                 // pass-0 weights: k = 0..63
        const v4f t = wr4[k];
        wv[2 * k] = t.xy; wv[2 * k + 1] = t.zw;
    }
    #pragma unroll
    for (int k = 0; k < 32; ++k) PIN2(wv[k]);
    __syncthreads();

    float acc[16];
    #pragma unroll
    for (int r = 0; r < 16; ++r) {                 // pass 0
        const v4f* xp = &xs4[r * 32];
        v2f a0 = {0.f, 0.f}, a1 = {0.f, 0.f};
        #pragma unroll
        for (int k = 0; k < 16; ++k) {
            const v4f v = xp[k];
            a0 = FMA2(wv[2 * k],     v.xy, a0);
            a1 = FMA2(wv[2 * k + 1], v.zw, a1);
        }
        const v2f s = a0 + a1;
        acc[r] = bias + s.x + s.y;
    }
    #pragma unroll
    for (int k = 0; k < 16; ++k) {                 // pass-1 weights: k = 64..127
        const v4f t = wr4[16 + k];
        wv[2 * k] = t.xy; wv[2 * k + 1] = t.zw;
    }
    #pragma unroll
    for (int k = 0; k < 32; ++k) PIN2(wv[k]);
    #pragma unroll
    for (int r = 0; r < 16; ++r) {                 // pass 1
        const v4f* xp = &xs4[r * 32] + 16;
        v2f a0 = {0.f, 0.f}, a1 = {0.f, 0.f};
        #pragma unroll
        for (int k = 0; k < 16; ++k) {
            const v4f v = xp[k];
            a0 = FMA2(wv[2 * k],     v.xy, a0);
            a1 = FMA2(wv[2 * k + 1], v.zw, a1);
        }
        const v2f s = a0 + a1;
        acc[r] += s.x + s.y;
    }

    // gate-interleaved layout: pos = hid*4 + gate (hid = j&127, gate = j>>7)
    float* dst = xg + ((size_t)b * Tc + tc0) * G4 + ((j & 127) << 2) + (j >> 7);
    #pragma unroll
    for (int r = 0; r < 16; ++r)
        dst[(size_t)r * G4] = acc[r];
}

// ---------------- recurrence: 512 threads, 8-lane group owns units (g, g+64)
__global__ __launch_bounds__(512)
__attribute__((amdgpu_waves_per_eu(2, 2)))
void lstm_rec_kernel(const float* __restrict__ xg, const float* __restrict__ h0,
                     const float* __restrict__ c0, const float* __restrict__ W_hh,
                     float* __restrict__ out, float* __restrict__ hstate,
                     float* __restrict__ cstate, int t0, int Tc) {
    // padded double buffer (R5 layout): value k at 20*(k>>4)+(k&15); chunk l
    // base = 80l B -> banks {0,20,8,28,16,4,24,12}: conflict-free reads.
    __shared__ __align__(16) float h_lds[2][160];
    const int t   = threadIdx.x;
    const int g   = t >> 3;                        // group 0..63
    const int l   = t & 7;                         // lane in group = k-chunk
    const int u   = l >> 2;                        // unit half
    const int sel = l & 3;                         // gate this lane owns
    const int b   = blockIdx.x;
    const int jj  = g + (u << 6);                  // this lane's unit (g or g+64)

    // 8 weight rows x 16-float chunk: rr 0..3 = unit g gates i,f,g,o;
    // rr 4..7 = unit g+64 gates i,f,g,o.
    const float* wl = W_hh + 16 * l;
    v2f W[8][8];
    #pragma unroll
    for (int rr = 0; rr < 8; ++rr) {
        const int row = (rr & 3) * 128 + g + ((rr >> 2) << 6);
        const v4f* wp = reinterpret_cast<const v4f*>(wl + (size_t)row * HID);
        #pragma unroll
        for (int k = 0; k < 4; ++k) {
            const v4f tw = wp[k];
            W[rr][2 * k] = tw.xy; W[rr][2 * k + 1] = tw.zw;
        }
    }

    float c = (t0 == 0) ? c0[b * HID + jj] : cstate[b * HID + jj];  // x4 in quad
    if (t < HID) {
        const int pi = 20 * (t >> 4) + (t & 15);
        h_lds[0][pi] = (t0 == 0) ? h0[b * HID + t] : hstate[b * HID + t];
    }
    __syncthreads();

    v2f hcv[8];
    #pragma unroll
    for (int k = 0; k < 4; ++k) {
        const v4f hv = *reinterpret_cast<const v4f*>(&h_lds[0][20 * l + 4 * k]);
        hcv[2 * k] = hv.xy; hcv[2 * k + 1] = hv.zw;
    }

    const float* xq   = xg  + (size_t)b * Tc * G4 + 4 * jj;  // gate-interleaved
    float*       outp = out + ((size_t)b * TT + t0) * HID + jj;
    v4f xn = *reinterpret_cast<const v4f*>(xq);

    for (int tc = 0; tc < Tc; ++tc) {
        // re-pin weights EVERY iteration: an AGPR home would cost 128
        // copies/iter, so the allocator must keep them in arch VGPRs.
        #pragma unroll
        for (int rr = 0; rr < 8; ++rr)
            #pragma unroll
            for (int k = 0; k < 8; ++k) PIN2(W[rr][k]);

        v4f xnn = xn;
        if (tc + 1 < Tc)                            // uniform branch
            xnn = *reinterpret_cast<const v4f*>(xq + (size_t)(tc + 1) * G4);

        v2f pp[8];
        #pragma unroll
        for (int rr = 0; rr < 8; ++rr) pp[rr] = (v2f){0.f, 0.f};
        #pragma unroll
        for (int rr = 0; rr < 8; ++rr)
            #pragma unroll
            for (int k = 0; k < 8; ++k)
                pp[rr] = FMA2(W[rr][k], hcv[k], pp[rr]);

        float p[8];
        #pragma unroll
        for (int rr = 0; rr < 8; ++rr) p[rr] = pp[rr].x + pp[rr].y;
        #pragma unroll
        for (int rr = 0; rr < 8; ++rr) BF8(p[rr])

        // lane l owns (unit u, gate sel): its summed pre-activation + xg term
        float xv = u == 0
            ? (sel == 0 ? p[0] : sel == 1 ? p[1] : sel == 2 ? p[2] : p[3])
            : (sel == 0 ? p[4] : sel == 1 ? p[5] : sel == 2 ? p[6] : p[7]);
        xv += (sel == 0 ? xn.x : sel == 1 ? xn.y : sel == 2 ? xn.z : xn.w);

        const float mm = (sel == 2) ? 2.f : 1.f;    // gate g: tanh = 2*sig(2x)-1
        const float e  = __expf(-xv * mm);
        float r  = 1.f / (1.f + e);
        r = (sel == 2) ? 2.f * r - 1.f : r;

        const float vi = dpp_mov<0x00>(r);          // quad bcast: i,f,g,o
        const float vf = dpp_mov<0x55>(r);
        const float vg = dpp_mov<0xAA>(r);
        const float vo = dpp_mov<0xFF>(r);
        c = fmaf(vf, c, vi * vg);
        const float th = 2.f / (1.f + __expf(-2.f * c)) - 1.f;  // tanh(c)
        const float h  = vo * th;

        const int nb = (tc + 1) & 1;
        if (sel == 0) {
            h_lds[nb][20 * (jj >> 4) + (jj & 15)] = h;
            outp[(size_t)tc * HID] = h;
        }
        __syncthreads();                            // ONE barrier per step
        #pragma unroll
        for (int k = 0; k < 4; ++k) {
            const v4f hv = *reinterpret_cast<const v4f*>(&h_lds[nb][20 * l + 4 * k]);
            hcv[2 * k] = hv.xy; hcv[2 * k + 1] = hv.zw;
        }
        xn = xnn;
    }
    if (sel == 0) cstate[b * HID + jj] = c;
    if (t < HID) {
        const int pi = 20 * (t >> 4) + (t & 15);
        hstate[b * HID + t] = h_lds[Tc & 1][pi];
    }
}

extern "C" void kernel_launch(void* const* d_in, const int* in_sizes, int n_in,
                              void* d_out, int out_size, void* d_ws, size_t ws_size,
                              hipStream_t stream) {
    const float* x    = (const float*)d_in[0];
    const float* h0   = (const float*)d_in[1];
    const float* c0   = (const float*)d_in[2];
    const float* W_ih = (const float*)d_in[3];
    const float* W_hh = (const float*)d_in[4];
    const float* b_ih = (const float*)d_in[5];
    const float* b_hh = (const float*)d_in[6];
    float* out = (float*)d_out;

    char*  ws     = (char*)d_ws;
    float* hstate = (float*)ws;                    // 32 KB
    float* cstate = (float*)(ws + 32768);          // 32 KB
    float* xg     = (float*)(ws + 65536);

    const size_t per_t = (size_t)BB * G4 * sizeof(float);   // 128 KB per timestep
    size_t avail = ws_size > 65536 ? ws_size - 65536 : 0;
    long long tc_ll = (long long)(avail / per_t);
    int Tc = tc_ll > TT ? TT : (int)tc_ll;
    Tc = (Tc / 64) * 64;
    if (Tc < 64) Tc = 64;

    for (int t0 = 0; t0 < TT; t0 += Tc) {
        const int Tcur = (TT - t0 < Tc) ? (TT - t0) : Tc;
        // xproj: 16 rows per block, 512 threads -> 4*Tcur blocks
        xproj_kernel<<<dim3(4 * Tcur), dim3(512), 0, stream>>>(x, W_ih, b_ih, b_hh,
                                                               xg, t0, Tcur);
        lstm_rec_kernel<<<dim3(BB), dim3(512), 0, stream>>>(xg, h0, c0, W_hh, out,
                                                            hstate, cstate, t0, Tcur);
    }
}

// Round 9
// 1970.371 us; speedup vs baseline: 1.3559x; 1.0802x over previous
//
#include <hip/hip_runtime.h>
#include <cstdint>
#include <cmath>

// LSTM: B=64, T=2048, H=128, gates=4H=512. f32 throughout (precision: per-step
// perturbations amplify ~1e4x over the 2048-step chain -- f16/bf16 recurrence
// would blow the 1.7e-2 threshold; no f32 MFMA on CDNA4 -> VALU recurrence).
//
// Round 9: R7 rec structure (1560us, issue-dense) + pk-fma dot (R8's VALU-work
// reduction) MINUS R8's per-iteration PIN walls (its regression source: 64 asm
// volatile scheduling barriers per step -> 30% idle). DPP adds use
// bound_ctrl=true so GCNDPPCombine can fuse mov_dpp+add -> v_add_f32_dpp.
//   rec: 64 blocks x 512 threads; 8-lane group owns units (g, g+64);
//        64 v2f weights/thread pinned once; butterfly reduce via DPP.
//   xproj: R8 version (LDS-staged, pk-fma, ~450us).

#define HID 128
#define G4  512
#define BB  64
#define TT  2048

typedef float v2f __attribute__((ext_vector_type(2)));
typedef float v4f __attribute__((ext_vector_type(4)));

#define PIN2(v) asm volatile("" : "+v"(v))
#define FMA2(A, B, C) __builtin_elementwise_fma((A), (B), (C))

// bound_ctrl=true: invalid lanes read src (irrelevant here -- all our DPP
// patterns read valid lanes) and enables mov_dpp+add -> v_add_f32_dpp fusion.
template<int CTRL>
__device__ __forceinline__ float dpp_mov(float v) {
    return __int_as_float(__builtin_amdgcn_update_dpp(
        0, __float_as_int(v), CTRL, 0xF, 0xF, true));
}
// 8-lane butterfly sum (validated R5/R7/R8): xor1=0xB1 quad_perm(1,0,3,2),
// xor2=0x4E quad_perm(2,3,0,1), 0x141 row_half_mirror (l^7: cross-quad after
// quads complete -> full 8-sum).
#define BF8(p) { p += dpp_mov<0xB1>(p); p += dpp_mov<0x4E>(p); p += dpp_mov<0x141>(p); }

// ---------------- xproj: LDS-staged, pk-fma inner loop (R8)
__global__ __launch_bounds__(512)
__attribute__((amdgpu_waves_per_eu(4, 4)))
void xproj_kernel(const float* __restrict__ x, const float* __restrict__ W_ih,
                  const float* __restrict__ b_ih, const float* __restrict__ b_hh,
                  float* __restrict__ xg, int t0, int Tc) {
    __shared__ __align__(16) v4f xs4[16 * 32];     // 16 rows x 128 f32 = 8 KB
    const int j    = threadIdx.x;                  // gate row 0..511
    const int row0 = blockIdx.x * 16;              // Tc % 16 == 0 -> tile in one b
    const int b    = row0 / Tc;
    const int tc0  = row0 % Tc;

    const float* xsrc = x + ((size_t)b * TT + (size_t)t0 + tc0) * HID;
    xs4[j] = reinterpret_cast<const v4f*>(xsrc)[j];   // 512 v4f = whole tile

    const float bias = b_ih[j] + b_hh[j];
    const v4f* wr4 = reinterpret_cast<const v4f*>(W_ih + (size_t)j * HID);

    v2f wv[32];
    #pragma unroll
    for (int k = 0; k < 16; ++k) {                 // pass-0 weights: k = 0..63
        const v4f t = wr4[k];
        wv[2 * k] = t.xy; wv[2 * k + 1] = t.zw;
    }
    #pragma unroll
    for (int k = 0; k < 32; ++k) PIN2(wv[k]);
    __syncthreads();

    float acc[16];
    #pragma unroll
    for (int r = 0; r < 16; ++r) {                 // pass 0
        const v4f* xp = &xs4[r * 32];
        v2f a0 = {0.f, 0.f}, a1 = {0.f, 0.f};
        #pragma unroll
        for (int k = 0; k < 16; ++k) {
            const v4f v = xp[k];
            a0 = FMA2(wv[2 * k],     v.xy, a0);
            a1 = FMA2(wv[2 * k + 1], v.zw, a1);
        }
        const v2f s = a0 + a1;
        acc[r] = bias + s.x + s.y;
    }
    #pragma unroll
    for (int k = 0; k < 16; ++k) {                 // pass-1 weights: k = 64..127
        const v4f t = wr4[16 + k];
        wv[2 * k] = t.xy; wv[2 * k + 1] = t.zw;
    }
    #pragma unroll
    for (int k = 0; k < 32; ++k) PIN2(wv[k]);
    #pragma unroll
    for (int r = 0; r < 16; ++r) {                 // pass 1
        const v4f* xp = &xs4[r * 32] + 16;
        v2f a0 = {0.f, 0.f}, a1 = {0.f, 0.f};
        #pragma unroll
        for (int k = 0; k < 16; ++k) {
            const v4f v = xp[k];
            a0 = FMA2(wv[2 * k],     v.xy, a0);
            a1 = FMA2(wv[2 * k + 1], v.zw, a1);
        }
        const v2f s = a0 + a1;
        acc[r] += s.x + s.y;
    }

    // gate-interleaved layout: pos = hid*4 + gate (hid = j&127, gate = j>>7)
    float* dst = xg + ((size_t)b * Tc + tc0) * G4 + ((j & 127) << 2) + (j >> 7);
    #pragma unroll
    for (int r = 0; r < 16; ++r)
        dst[(size_t)r * G4] = acc[r];
}

// ---------------- recurrence: 512 threads, 8-lane group owns units (g, g+64)
__global__ __launch_bounds__(512)
__attribute__((amdgpu_waves_per_eu(2, 2)))
void lstm_rec_kernel(const float* __restrict__ xg, const float* __restrict__ h0,
                     const float* __restrict__ c0, const float* __restrict__ W_hh,
                     float* __restrict__ out, float* __restrict__ hstate,
                     float* __restrict__ cstate, int t0, int Tc) {
    // padded double buffer (R5 layout): value k at 20*(k>>4)+(k&15); chunk l
    // base = 80l B -> banks {0,20,8,28,16,4,24,12}: conflict-free reads.
    __shared__ __align__(16) float h_lds[2][160];
    const int t   = threadIdx.x;
    const int g   = t >> 3;                        // group 0..63
    const int l   = t & 7;                         // lane in group = k-chunk
    const int u   = l >> 2;                        // unit half
    const int sel = l & 3;                         // gate this lane owns
    const int b   = blockIdx.x;
    const int jj  = g + (u << 6);                  // this lane's unit (g or g+64)

    // 8 weight rows x 16-float chunk: rr 0..3 = unit g gates i,f,g,o;
    // rr 4..7 = unit g+64 gates i,f,g,o.
    const float* wl = W_hh + 16 * l;
    v2f W[8][8];
    #pragma unroll
    for (int rr = 0; rr < 8; ++rr) {
        const int row = (rr & 3) * 128 + g + ((rr >> 2) << 6);
        const v4f* wp = reinterpret_cast<const v4f*>(wl + (size_t)row * HID);
        #pragma unroll
        for (int k = 0; k < 4; ++k) {
            const v4f tw = wp[k];
            W[rr][2 * k] = tw.xy; W[rr][2 * k + 1] = tw.zw;
        }
    }
    // pin ONCE (not per-iteration -- R8's per-step asm walls were the
    // regression: 64 scheduling barriers/step -> 30% idle).
    #pragma unroll
    for (int rr = 0; rr < 8; ++rr)
        #pragma unroll
        for (int k = 0; k < 8; ++k) PIN2(W[rr][k]);

    float c = (t0 == 0) ? c0[b * HID + jj] : cstate[b * HID + jj];  // x4 in quad
    if (t < HID) {
        const int pi = 20 * (t >> 4) + (t & 15);
        h_lds[0][pi] = (t0 == 0) ? h0[b * HID + t] : hstate[b * HID + t];
    }
    __syncthreads();

    v2f hcv[8];
    #pragma unroll
    for (int k = 0; k < 4; ++k) {
        const v4f hv = *reinterpret_cast<const v4f*>(&h_lds[0][20 * l + 4 * k]);
        hcv[2 * k] = hv.xy; hcv[2 * k + 1] = hv.zw;
    }

    const float* xq   = xg  + (size_t)b * Tc * G4 + 4 * jj;  // gate-interleaved
    float*       outp = out + ((size_t)b * TT + t0) * HID + jj;
    v4f xn = *reinterpret_cast<const v4f*>(xq);

    for (int tc = 0; tc < Tc; ++tc) {
        v4f xnn = xn;
        if (tc + 1 < Tc)                            // uniform branch
            xnn = *reinterpret_cast<const v4f*>(xq + (size_t)(tc + 1) * G4);

        v2f pp[8];
        #pragma unroll
        for (int rr = 0; rr < 8; ++rr) pp[rr] = (v2f){0.f, 0.f};
        #pragma unroll
        for (int rr = 0; rr < 8; ++rr)
            #pragma unroll
            for (int k = 0; k < 8; ++k)
                pp[rr] = FMA2(W[rr][k], hcv[k], pp[rr]);

        float p[8];
        #pragma unroll
        for (int rr = 0; rr < 8; ++rr) p[rr] = pp[rr].x + pp[rr].y;
        #pragma unroll
        for (int rr = 0; rr < 8; ++rr) BF8(p[rr])

        // lane l owns (unit u, gate sel): its summed pre-activation + xg term
        float xv = u == 0
            ? (sel == 0 ? p[0] : sel == 1 ? p[1] : sel == 2 ? p[2] : p[3])
            : (sel == 0 ? p[4] : sel == 1 ? p[5] : sel == 2 ? p[6] : p[7]);
        xv += (sel == 0 ? xn.x : sel == 1 ? xn.y : sel == 2 ? xn.z : xn.w);

        const float mm = (sel == 2) ? 2.f : 1.f;    // gate g: tanh = 2*sig(2x)-1
        const float e  = __expf(-xv * mm);
        float r  = 1.f / (1.f + e);
        r = (sel == 2) ? 2.f * r - 1.f : r;

        const float vi = dpp_mov<0x00>(r);          // quad bcast: i,f,g,o
        const float vf = dpp_mov<0x55>(r);
        const float vg = dpp_mov<0xAA>(r);
        const float vo = dpp_mov<0xFF>(r);
        c = fmaf(vf, c, vi * vg);
        const float th = 2.f / (1.f + __expf(-2.f * c)) - 1.f;  // tanh(c)
        const float h  = vo * th;

        const int nb = (tc + 1) & 1;
        if (sel == 0) {
            h_lds[nb][20 * (jj >> 4) + (jj & 15)] = h;
            outp[(size_t)tc * HID] = h;
        }
        __syncthreads();                            // ONE barrier per step
        #pragma unroll
        for (int k = 0; k < 4; ++k) {
            const v4f hv = *reinterpret_cast<const v4f*>(&h_lds[nb][20 * l + 4 * k]);
            hcv[2 * k] = hv.xy; hcv[2 * k + 1] = hv.zw;
        }
        xn = xnn;
    }
    if (sel == 0) cstate[b * HID + jj] = c;
    if (t < HID) {
        const int pi = 20 * (t >> 4) + (t & 15);
        hstate[b * HID + t] = h_lds[Tc & 1][pi];
    }
}

extern "C" void kernel_launch(void* const* d_in, const int* in_sizes, int n_in,
                              void* d_out, int out_size, void* d_ws, size_t ws_size,
                              hipStream_t stream) {
    const float* x    = (const float*)d_in[0];
    const float* h0   = (const float*)d_in[1];
    const float* c0   = (const float*)d_in[2];
    const float* W_ih = (const float*)d_in[3];
    const float* W_hh = (const float*)d_in[4];
    const float* b_ih = (const float*)d_in[5];
    const float* b_hh = (const float*)d_in[6];
    float* out = (float*)d_out;

    char*  ws     = (char*)d_ws;
    float* hstate = (float*)ws;                    // 32 KB
    float* cstate = (float*)(ws + 32768);          // 32 KB
    float* xg     = (float*)(ws + 65536);

    const size_t per_t = (size_t)BB * G4 * sizeof(float);   // 128 KB per timestep
    size_t avail = ws_size > 65536 ? ws_size - 65536 : 0;
    long long tc_ll = (long long)(avail / per_t);
    int Tc = tc_ll > TT ? TT : (int)tc_ll;
    Tc = (Tc / 64) * 64;
    if (Tc < 64) Tc = 64;

    for (int t0 = 0; t0 < TT; t0 += Tc) {
        const int Tcur = (TT - t0 < Tc) ? (TT - t0) : Tc;
        // xproj: 16 rows per block, 512 threads -> 4*Tcur blocks
        xproj_kernel<<<dim3(4 * Tcur), dim3(512), 0, stream>>>(x, W_ih, b_ih, b_hh,
                                                               xg, t0, Tcur);
        lstm_rec_kernel<<<dim3(BB), dim3(512), 0, stream>>>(xg, h0, c0, W_hh, out,
                                                            hstate, cstate, t0, Tcur);
    }
}

// Round 10
// 1718.616 us; speedup vs baseline: 1.5545x; 1.1465x over previous
//
#include <hip/hip_runtime.h>
#include <cstdint>
#include <cmath>

// LSTM: B=64, T=2048, H=128, gates=4H=512. f32 throughout.
//
// Round 10: rec restructured for issue-count + latency hiding.
//  - 1024 threads = 128 groups of 8 lanes; group g owns unit g (4 gate rows);
//    lane l owns cols [16l,16l+16) -> 64 weight floats (32 v2f), 4 partials,
//    12 DPP (vs 24), 3-cndmask select (hoisted lane masks).
//  - per-lane SCALAR xg load (lane's own gate only) -> no xn select.
//  - v_rcp_f32 via __builtin_amdgcn_rcpf (plain 1/x was emitting the ~9-inst
//    IEEE div sequence -- 3x per step since R1!) and v_exp_f32 via
//    __builtin_amdgcn_exp2f with per-lane pre-folded scale constants.
//  - 4 waves/SIMD (vs 2): the ~400cy serial tail (reduce->exp->c->tanh->LDS->
//    barrier->ds_read) hides under other waves' dot issue.
// xproj: unchanged from R9 (~430us).

#define HID 128
#define G4  512
#define BB  64
#define TT  2048

typedef float v2f __attribute__((ext_vector_type(2)));
typedef float v4f __attribute__((ext_vector_type(4)));

#define PIN2(v) asm volatile("" : "+v"(v))
#define FMA2(A, B, C) __builtin_elementwise_fma((A), (B), (C))

#define LOG2E  1.442695041f

// bound_ctrl=true enables mov_dpp+add -> v_add_f32_dpp fusion.
template<int CTRL>
__device__ __forceinline__ float dpp_mov(float v) {
    return __int_as_float(__builtin_amdgcn_update_dpp(
        0, __float_as_int(v), CTRL, 0xF, 0xF, true));
}
// 8-lane butterfly sum (validated R5-R9): xor1=0xB1 quad_perm(1,0,3,2),
// xor2=0x4E quad_perm(2,3,0,1), 0x141 row_half_mirror.
#define BF8(p) { p += dpp_mov<0xB1>(p); p += dpp_mov<0x4E>(p); p += dpp_mov<0x141>(p); }

// ---------------- xproj: LDS-staged, pk-fma inner loop (R8/R9)
__global__ __launch_bounds__(512)
__attribute__((amdgpu_waves_per_eu(4, 4)))
void xproj_kernel(const float* __restrict__ x, const float* __restrict__ W_ih,
                  const float* __restrict__ b_ih, const float* __restrict__ b_hh,
                  float* __restrict__ xg, int t0, int Tc) {
    __shared__ __align__(16) v4f xs4[16 * 32];     // 16 rows x 128 f32 = 8 KB
    const int j    = threadIdx.x;                  // gate row 0..511
    const int row0 = blockIdx.x * 16;              // Tc % 16 == 0 -> tile in one b
    const int b    = row0 / Tc;
    const int tc0  = row0 % Tc;

    const float* xsrc = x + ((size_t)b * TT + (size_t)t0 + tc0) * HID;
    xs4[j] = reinterpret_cast<const v4f*>(xsrc)[j];   // 512 v4f = whole tile

    const float bias = b_ih[j] + b_hh[j];
    const v4f* wr4 = reinterpret_cast<const v4f*>(W_ih + (size_t)j * HID);

    v2f wv[32];
    #pragma unroll
    for (int k = 0; k < 16; ++k) {                 // pass-0 weights: k = 0..63
        const v4f t = wr4[k];
        wv[2 * k] = t.xy; wv[2 * k + 1] = t.zw;
    }
    #pragma unroll
    for (int k = 0; k < 32; ++k) PIN2(wv[k]);
    __syncthreads();

    float acc[16];
    #pragma unroll
    for (int r = 0; r < 16; ++r) {                 // pass 0
        const v4f* xp = &xs4[r * 32];
        v2f a0 = {0.f, 0.f}, a1 = {0.f, 0.f};
        #pragma unroll
        for (int k = 0; k < 16; ++k) {
            const v4f v = xp[k];
            a0 = FMA2(wv[2 * k],     v.xy, a0);
            a1 = FMA2(wv[2 * k + 1], v.zw, a1);
        }
        const v2f s = a0 + a1;
        acc[r] = bias + s.x + s.y;
    }
    #pragma unroll
    for (int k = 0; k < 16; ++k) {                 // pass-1 weights: k = 64..127
        const v4f t = wr4[16 + k];
        wv[2 * k] = t.xy; wv[2 * k + 1] = t.zw;
    }
    #pragma unroll
    for (int k = 0; k < 32; ++k) PIN2(wv[k]);
    #pragma unroll
    for (int r = 0; r < 16; ++r) {                 // pass 1
        const v4f* xp = &xs4[r * 32] + 16;
        v2f a0 = {0.f, 0.f}, a1 = {0.f, 0.f};
        #pragma unroll
        for (int k = 0; k < 16; ++k) {
            const v4f v = xp[k];
            a0 = FMA2(wv[2 * k],     v.xy, a0);
            a1 = FMA2(wv[2 * k + 1], v.zw, a1);
        }
        const v2f s = a0 + a1;
        acc[r] += s.x + s.y;
    }

    // gate-interleaved layout: pos = hid*4 + gate (hid = j&127, gate = j>>7)
    float* dst = xg + ((size_t)b * Tc + tc0) * G4 + ((j & 127) << 2) + (j >> 7);
    #pragma unroll
    for (int r = 0; r < 16; ++r)
        dst[(size_t)r * G4] = acc[r];
}

// ---------------- recurrence: 1024 threads, 8-lane group owns ONE unit
__global__ __launch_bounds__(1024)
__attribute__((amdgpu_waves_per_eu(4, 4)))
void lstm_rec_kernel(const float* __restrict__ xg, const float* __restrict__ h0,
                     const float* __restrict__ c0, const float* __restrict__ W_hh,
                     float* __restrict__ out, float* __restrict__ hstate,
                     float* __restrict__ cstate, int t0, int Tc) {
    // padded double buffer (R5 layout): value k at 20*(k>>4)+(k&15); chunk l
    // base = 80l B -> banks {0,20,8,28,16,4,24,12}: conflict-free, and all
    // groups share chunk l -> 8-address broadcast reads.
    __shared__ __align__(16) float h_lds[2][160];
    const int t   = threadIdx.x;
    const int g   = t >> 3;                        // group = unit 0..127
    const int l   = t & 7;                         // k-chunk lane
    const int sel = l & 3;                         // gate this lane owns
    const int b   = blockIdx.x;

    // weights: 4 gate rows (i,f,g,o) of unit g, cols [16l,16l+16)
    const float* wl = W_hh + 16 * l;
    v2f W[4][8];
    #pragma unroll
    for (int q = 0; q < 4; ++q) {
        const v4f* wp = reinterpret_cast<const v4f*>(wl + (size_t)(q * 128 + g) * HID);
        #pragma unroll
        for (int k = 0; k < 4; ++k) {
            const v4f tw = wp[k];
            W[q][2 * k] = tw.xy; W[q][2 * k + 1] = tw.zw;
        }
    }
    #pragma unroll
    for (int q = 0; q < 4; ++q)
        #pragma unroll
        for (int k = 0; k < 8; ++k) PIN2(W[q][k]);  // pin ONCE (R8 lesson)

    // per-lane gate constants (gate 2 = tanh = 2*sigmoid(2x)-1)
    const bool  la   = (l & 1) != 0;               // hoisted lane masks
    const bool  lb   = (l & 2) != 0;
    const float negK = (sel == 2) ? -2.f * LOG2E : -LOG2E;  // exp2 scale
    const float gA   = (sel == 2) ? 2.f : 1.f;
    const float gB   = (sel == 2) ? -1.f : 0.f;

    float c = (t0 == 0) ? c0[b * HID + g] : cstate[b * HID + g];  // x8 in group
    if (t < HID) {
        const int pi = 20 * (t >> 4) + (t & 15);
        h_lds[0][pi] = (t0 == 0) ? h0[b * HID + t] : hstate[b * HID + t];
    }
    __syncthreads();

    v2f hcv[8];
    #pragma unroll
    for (int k = 0; k < 4; ++k) {
        const v4f hv = *reinterpret_cast<const v4f*>(&h_lds[0][20 * l + 4 * k]);
        hcv[2 * k] = hv.xy; hcv[2 * k + 1] = hv.zw;
    }

    // per-lane SCALAR xg stream: this lane's gate of unit g
    const float* xq   = xg  + (size_t)b * Tc * G4 + 4 * g + sel;
    float*       outp = out + ((size_t)b * TT + t0) * HID + g;
    float xn = xq[0];

    for (int tc = 0; tc < Tc; ++tc) {
        float xnn = xn;
        if (tc + 1 < Tc)                            // uniform branch
            xnn = xq[(size_t)(tc + 1) * G4];        // issue next-step load early

        v2f pp0 = {0.f, 0.f}, pp1 = {0.f, 0.f}, pp2 = {0.f, 0.f}, pp3 = {0.f, 0.f};
        #pragma unroll
        for (int k = 0; k < 8; ++k) {
            pp0 = FMA2(W[0][k], hcv[k], pp0);
            pp1 = FMA2(W[1][k], hcv[k], pp1);
            pp2 = FMA2(W[2][k], hcv[k], pp2);
            pp3 = FMA2(W[3][k], hcv[k], pp3);
        }
        float p0 = pp0.x + pp0.y, p1 = pp1.x + pp1.y;
        float p2 = pp2.x + pp2.y, p3 = pp3.x + pp3.y;
        BF8(p0) BF8(p1) BF8(p2) BF8(p3)             // all 8 lanes: full sums

        const float t01 = la ? p1 : p0;
        const float t23 = la ? p3 : p2;
        const float xv  = (lb ? t23 : t01) + xn;    // lane's gate pre-activation

        // r = sigmoid(xv) (sel!=2) or tanh(xv) (sel==2), 5 insts:
        const float e = __builtin_amdgcn_exp2f(xv * negK);
        float r = __builtin_amdgcn_rcpf(1.f + e);
        r = fmaf(r, gA, gB);

        const float vi = dpp_mov<0x00>(r);          // quad bcast: i,f,g,o
        const float vf = dpp_mov<0x55>(r);
        const float vg = dpp_mov<0xAA>(r);
        const float vo = dpp_mov<0xFF>(r);
        c = fmaf(vf, c, vi * vg);
        const float e2 = __builtin_amdgcn_exp2f(c * (-2.f * LOG2E));
        const float th = fmaf(2.f, __builtin_amdgcn_rcpf(1.f + e2), -1.f); // tanh(c)
        const float h  = vo * th;

        const int nb = (tc + 1) & 1;
        if (l == 0) {                               // one writer per unit
            h_lds[nb][20 * (g >> 4) + (g & 15)] = h;
            outp[(size_t)tc * HID] = h;
        }
        __syncthreads();                            // ONE barrier per step
        #pragma unroll
        for (int k = 0; k < 4; ++k) {
            const v4f hv = *reinterpret_cast<const v4f*>(&h_lds[nb][20 * l + 4 * k]);
            hcv[2 * k] = hv.xy; hcv[2 * k + 1] = hv.zw;
        }
        xn = xnn;
    }
    if (l == 0) cstate[b * HID + g] = c;
    if (t < HID) {
        const int pi = 20 * (t >> 4) + (t & 15);
        hstate[b * HID + t] = h_lds[Tc & 1][pi];
    }
}

extern "C" void kernel_launch(void* const* d_in, const int* in_sizes, int n_in,
                              void* d_out, int out_size, void* d_ws, size_t ws_size,
                              hipStream_t stream) {
    const float* x    = (const float*)d_in[0];
    const float* h0   = (const float*)d_in[1];
    const float* c0   = (const float*)d_in[2];
    const float* W_ih = (const float*)d_in[3];
    const float* W_hh = (const float*)d_in[4];
    const float* b_ih = (const float*)d_in[5];
    const float* b_hh = (const float*)d_in[6];
    float* out = (float*)d_out;

    char*  ws     = (char*)d_ws;
    float* hstate = (float*)ws;                    // 32 KB
    float* cstate = (float*)(ws + 32768);          // 32 KB
    float* xg     = (float*)(ws + 65536);

    const size_t per_t = (size_t)BB * G4 * sizeof(float);   // 128 KB per timestep
    size_t avail = ws_size > 65536 ? ws_size - 65536 : 0;
    long long tc_ll = (long long)(avail / per_t);
    int Tc = tc_ll > TT ? TT : (int)tc_ll;
    Tc = (Tc / 64) * 64;
    if (Tc < 64) Tc = 64;

    for (int t0 = 0; t0 < TT; t0 += Tc) {
        const int Tcur = (TT - t0 < Tc) ? (TT - t0) : Tc;
        // xproj: 16 rows per block, 512 threads -> 4*Tcur blocks
        xproj_kernel<<<dim3(4 * Tcur), dim3(512), 0, stream>>>(x, W_ih, b_ih, b_hh,
                                                               xg, t0, Tcur);
        lstm_rec_kernel<<<dim3(BB), dim3(1024), 0, stream>>>(xg, h0, c0, W_hh, out,
                                                             hstate, cstate, t0, Tcur);
    }
}

// Round 11
// 1673.907 us; speedup vs baseline: 1.5960x; 1.0267x over previous
//
#include <hip/hip_runtime.h>
#include <cstdint>
#include <cmath>

// LSTM: B=64, T=2048, H=128, gates=4H=512. f32 throughout.
//
// Round 11: producer-consumer FUSION. R10 ran xproj (~410us, 256 CUs) serially
// before rec (~1310us, only 64 CUs busy). One fused launch:
//   blocks 0..63   = rec chains (R10 body unchanged), 1 block/CU (96KB LDS).
//   blocks 64..4159 = xproj tiles (32 rows each) on the other ~192 CUs.
// xproj tile (b, window w = 32 steps) publishes flags[w*64+b] with a
// device-scope RELEASE store (wbL2 -> cross-XCD visible); rec ACQUIRE-spins
// (invalidates L1/L2) one window ahead of consumption. Tiles are round-robin
// over b so all chains' early windows are produced first. Deadlock-free under
// any dispatch order: producers never wait; 64 spinning consumers < 256 CUs.
// Fallback (ws too small for full-T xg): R10 chunked two-kernel path.

#define HID 128
#define G4  512
#define BB  64
#define TT  2048

typedef float v2f __attribute__((ext_vector_type(2)));
typedef float v4f __attribute__((ext_vector_type(4)));

#define PIN2(v) asm volatile("" : "+v"(v))
#define FMA2(A, B, C) __builtin_elementwise_fma((A), (B), (C))
#define LOG2E  1.442695041f

template<int CTRL>
__device__ __forceinline__ float dpp_mov(float v) {
    return __int_as_float(__builtin_amdgcn_update_dpp(
        0, __float_as_int(v), CTRL, 0xF, 0xF, true));
}
// 8-lane butterfly sum (validated R5-R10).
#define BF8(p) { p += dpp_mov<0xB1>(p); p += dpp_mov<0x4E>(p); p += dpp_mov<0x141>(p); }

// ---- shared xproj per-thread math: gate row j over 16 rows from LDS ----
// (two 64-col passes, 32 v2f pinned weights, pk-fma; identical numerics R8-R10)
__device__ __forceinline__ void xproj_rows16(const v4f* __restrict__ xrows,  // 16 rows x 32 v4f
                                             const float* __restrict__ W_ih,
                                             float bias, int j, float* __restrict__ acc) {
    const v4f* wr4 = reinterpret_cast<const v4f*>(W_ih + (size_t)j * HID);
    v2f wv[32];
    #pragma unroll
    for (int k = 0; k < 16; ++k) { const v4f t = wr4[k]; wv[2*k] = t.xy; wv[2*k+1] = t.zw; }
    #pragma unroll
    for (int k = 0; k < 32; ++k) PIN2(wv[k]);
    #pragma unroll
    for (int r = 0; r < 16; ++r) {                 // pass 0: k=0..63
        const v4f* xp = xrows + r * 32;
        v2f a0 = {0.f,0.f}, a1 = {0.f,0.f};
        #pragma unroll
        for (int k = 0; k < 16; ++k) {
            const v4f v = xp[k];
            a0 = FMA2(wv[2*k], v.xy, a0); a1 = FMA2(wv[2*k+1], v.zw, a1);
        }
        const v2f s = a0 + a1;
        acc[r] = bias + s.x + s.y;
    }
    #pragma unroll
    for (int k = 0; k < 16; ++k) { const v4f t = wr4[16+k]; wv[2*k] = t.xy; wv[2*k+1] = t.zw; }
    #pragma unroll
    for (int k = 0; k < 32; ++k) PIN2(wv[k]);
    #pragma unroll
    for (int r = 0; r < 16; ++r) {                 // pass 1: k=64..127
        const v4f* xp = xrows + r * 32 + 16;
        v2f a0 = {0.f,0.f}, a1 = {0.f,0.f};
        #pragma unroll
        for (int k = 0; k < 16; ++k) {
            const v4f v = xp[k];
            a0 = FMA2(wv[2*k], v.xy, a0); a1 = FMA2(wv[2*k+1], v.zw, a1);
        }
        const v2f s = a0 + a1;
        acc[r] += s.x + s.y;
    }
}

// ================= FUSED kernel =================
__global__ __launch_bounds__(1024)
__attribute__((amdgpu_waves_per_eu(4, 4)))
void lstm_fused_kernel(const float* __restrict__ x, const float* __restrict__ h0,
                       const float* __restrict__ c0, const float* __restrict__ W_ih,
                       const float* __restrict__ W_hh, const float* __restrict__ b_ih,
                       const float* __restrict__ b_hh, float* __restrict__ out,
                       float* __restrict__ xg, int* __restrict__ flags) {
    __shared__ __align__(16) float lds_pool[24576];   // 96 KB -> 1 block/CU
    const int t = threadIdx.x;

    if (blockIdx.x >= BB) {
        // ---------- producer: one 32-row xproj tile ----------
        const int tile = blockIdx.x - BB;
        const int bb   = tile & 63;                // batch
        const int w    = tile >> 6;                // 32-step window
        const int tc0  = w * 32;
        v4f* xs4 = reinterpret_cast<v4f*>(lds_pool);          // 1024 v4f = 16 KB
        const float* xsrc = x + ((size_t)bb * TT + tc0) * HID;
        xs4[t] = reinterpret_cast<const v4f*>(xsrc)[t];       // stage 32 rows
        const int j  = t & 511;                    // gate row
        const int rg = t >> 9;                     // row-group 0/1
        const float bias = b_ih[j] + b_hh[j];
        __syncthreads();

        float acc[16];
        xproj_rows16(xs4 + rg * 16 * 32, W_ih, bias, j, acc);

        // gate-interleaved: pos = hid*4 + gate
        float* dst = xg + ((size_t)bb * TT + tc0 + rg * 16) * G4
                        + ((j & 127) << 2) + (j >> 7);
        #pragma unroll
        for (int r = 0; r < 16; ++r)
            dst[(size_t)r * G4] = acc[r];

        __syncthreads();                           // all waves' stores drained
        if (t == 0)
            __hip_atomic_store(&flags[tile], 1, __ATOMIC_RELEASE,
                               __HIP_MEMORY_SCOPE_AGENT);
        return;
    }

    // ---------- consumer: recurrence chain b (R10 body) ----------
    const int g   = t >> 3;                        // unit 0..127
    const int l   = t & 7;                         // k-chunk lane
    const int sel = l & 3;                         // gate this lane owns
    const int b   = blockIdx.x;
    float* hl = lds_pool;                          // h_lds[2][160] overlay

    const float* wl = W_hh + 16 * l;
    v2f W[4][8];
    #pragma unroll
    for (int q = 0; q < 4; ++q) {
        const v4f* wp = reinterpret_cast<const v4f*>(wl + (size_t)(q * 128 + g) * HID);
        #pragma unroll
        for (int k = 0; k < 4; ++k) { const v4f tw = wp[k]; W[q][2*k] = tw.xy; W[q][2*k+1] = tw.zw; }
    }
    #pragma unroll
    for (int q = 0; q < 4; ++q)
        #pragma unroll
        for (int k = 0; k < 8; ++k) PIN2(W[q][k]);

    const bool  la   = (l & 1) != 0;
    const bool  lb   = (l & 2) != 0;
    const float negK = (sel == 2) ? -2.f * LOG2E : -LOG2E;
    const float gA   = (sel == 2) ? 2.f : 1.f;
    const float gB   = (sel == 2) ? -1.f : 0.f;

    float c = c0[b * HID + g];
    if (t < HID) {
        const int pi = 20 * (t >> 4) + (t & 15);
        hl[pi] = h0[b * HID + t];
    }
    __syncthreads();

    v2f hcv[8];
    #pragma unroll
    for (int k = 0; k < 4; ++k) {
        const v4f hv = *reinterpret_cast<const v4f*>(&hl[20 * l + 4 * k]);
        hcv[2*k] = hv.xy; hcv[2*k+1] = hv.zw;
    }

    // wait for windows 0 and 1 of this b (covers steps 0..63 incl. prefetch)
    #define WAITTILE(idx) { if (t == 0) {                                        \
        while (__hip_atomic_load(&flags[idx], __ATOMIC_ACQUIRE,                  \
                                 __HIP_MEMORY_SCOPE_AGENT) == 0)                 \
            __builtin_amdgcn_s_sleep(8); }                                       \
        __syncthreads(); }
    WAITTILE(b)                                    // w=0
    WAITTILE(64 + b)                               // w=1

    const float* xq   = xg  + (size_t)b * TT * G4 + 4 * g + sel;
    float*       outp = out + (size_t)b * TT * HID + g;
    float xn = xq[0];

    for (int tc = 0; tc < TT; ++tc) {
        if ((tc & 31) == 0 && tc != 0) {           // uniform: window boundary
            const int w1 = (tc >> 5) + 1;          // cover upcoming prefetches
            if (w1 < 64) WAITTILE(w1 * 64 + b)
        }
        float xnn = xn;
        if (tc + 1 < TT)
            xnn = xq[(size_t)(tc + 1) * G4];       // issue next-step load early

        v2f pp0 = {0.f,0.f}, pp1 = {0.f,0.f}, pp2 = {0.f,0.f}, pp3 = {0.f,0.f};
        #pragma unroll
        for (int k = 0; k < 8; ++k) {
            pp0 = FMA2(W[0][k], hcv[k], pp0);
            pp1 = FMA2(W[1][k], hcv[k], pp1);
            pp2 = FMA2(W[2][k], hcv[k], pp2);
            pp3 = FMA2(W[3][k], hcv[k], pp3);
        }
        float p0 = pp0.x + pp0.y, p1 = pp1.x + pp1.y;
        float p2 = pp2.x + pp2.y, p3 = pp3.x + pp3.y;
        BF8(p0) BF8(p1) BF8(p2) BF8(p3)

        const float t01 = la ? p1 : p0;
        const float t23 = la ? p3 : p2;
        const float xv  = (lb ? t23 : t01) + xn;

        const float e = __builtin_amdgcn_exp2f(xv * negK);
        float r = __builtin_amdgcn_rcpf(1.f + e);
        r = fmaf(r, gA, gB);

        const float vi = dpp_mov<0x00>(r);
        const float vf = dpp_mov<0x55>(r);
        const float vg = dpp_mov<0xAA>(r);
        const float vo = dpp_mov<0xFF>(r);
        c = fmaf(vf, c, vi * vg);
        const float e2 = __builtin_amdgcn_exp2f(c * (-2.f * LOG2E));
        const float th = fmaf(2.f, __builtin_amdgcn_rcpf(1.f + e2), -1.f);
        const float h  = vo * th;

        const int nb = (tc + 1) & 1;
        if (l == 0) {
            hl[nb * 160 + 20 * (g >> 4) + (g & 15)] = h;
            outp[(size_t)tc * HID] = h;
        }
        __syncthreads();                           // ONE barrier per step
        #pragma unroll
        for (int k = 0; k < 4; ++k) {
            const v4f hv = *reinterpret_cast<const v4f*>(&hl[nb * 160 + 20 * l + 4 * k]);
            hcv[2*k] = hv.xy; hcv[2*k+1] = hv.zw;
        }
        xn = xnn;
    }
    #undef WAITTILE
}

// ================= fallback: R10 chunked two-kernel path =================
__global__ __launch_bounds__(512)
__attribute__((amdgpu_waves_per_eu(4, 4)))
void xproj_kernel(const float* __restrict__ x, const float* __restrict__ W_ih,
                  const float* __restrict__ b_ih, const float* __restrict__ b_hh,
                  float* __restrict__ xg, int t0, int Tc) {
    __shared__ __align__(16) v4f xs4[16 * 32];
    const int j    = threadIdx.x;
    const int row0 = blockIdx.x * 16;
    const int b    = row0 / Tc;
    const int tc0  = row0 % Tc;
    const float* xsrc = x + ((size_t)b * TT + (size_t)t0 + tc0) * HID;
    xs4[j] = reinterpret_cast<const v4f*>(xsrc)[j];
    const float bias = b_ih[j] + b_hh[j];
    __syncthreads();
    float acc[16];
    xproj_rows16(xs4, W_ih, bias, j, acc);
    float* dst = xg + ((size_t)b * Tc + tc0) * G4 + ((j & 127) << 2) + (j >> 7);
    #pragma unroll
    for (int r = 0; r < 16; ++r)
        dst[(size_t)r * G4] = acc[r];
}

__global__ __launch_bounds__(1024)
__attribute__((amdgpu_waves_per_eu(4, 4)))
void lstm_rec_kernel(const float* __restrict__ xg, const float* __restrict__ h0,
                     const float* __restrict__ c0, const float* __restrict__ W_hh,
                     float* __restrict__ out, float* __restrict__ hstate,
                     float* __restrict__ cstate, int t0, int Tc) {
    __shared__ __align__(16) float h_lds[2][160];
    const int t   = threadIdx.x;
    const int g   = t >> 3;
    const int l   = t & 7;
    const int sel = l & 3;
    const int b   = blockIdx.x;
    const float* wl = W_hh + 16 * l;
    v2f W[4][8];
    #pragma unroll
    for (int q = 0; q < 4; ++q) {
        const v4f* wp = reinterpret_cast<const v4f*>(wl + (size_t)(q * 128 + g) * HID);
        #pragma unroll
        for (int k = 0; k < 4; ++k) { const v4f tw = wp[k]; W[q][2*k] = tw.xy; W[q][2*k+1] = tw.zw; }
    }
    #pragma unroll
    for (int q = 0; q < 4; ++q)
        #pragma unroll
        for (int k = 0; k < 8; ++k) PIN2(W[q][k]);
    const bool  la   = (l & 1) != 0;
    const bool  lb   = (l & 2) != 0;
    const float negK = (sel == 2) ? -2.f * LOG2E : -LOG2E;
    const float gA   = (sel == 2) ? 2.f : 1.f;
    const float gB   = (sel == 2) ? -1.f : 0.f;
    float c = (t0 == 0) ? c0[b * HID + g] : cstate[b * HID + g];
    if (t < HID) {
        const int pi = 20 * (t >> 4) + (t & 15);
        h_lds[0][pi] = (t0 == 0) ? h0[b * HID + t] : hstate[b * HID + t];
    }
    __syncthreads();
    v2f hcv[8];
    #pragma unroll
    for (int k = 0; k < 4; ++k) {
        const v4f hv = *reinterpret_cast<const v4f*>(&h_lds[0][20 * l + 4 * k]);
        hcv[2*k] = hv.xy; hcv[2*k+1] = hv.zw;
    }
    const float* xq   = xg  + (size_t)b * Tc * G4 + 4 * g + sel;
    float*       outp = out + ((size_t)b * TT + t0) * HID + g;
    float xn = xq[0];
    for (int tc = 0; tc < Tc; ++tc) {
        float xnn = xn;
        if (tc + 1 < Tc)
            xnn = xq[(size_t)(tc + 1) * G4];
        v2f pp0 = {0.f,0.f}, pp1 = {0.f,0.f}, pp2 = {0.f,0.f}, pp3 = {0.f,0.f};
        #pragma unroll
        for (int k = 0; k < 8; ++k) {
            pp0 = FMA2(W[0][k], hcv[k], pp0);
            pp1 = FMA2(W[1][k], hcv[k], pp1);
            pp2 = FMA2(W[2][k], hcv[k], pp2);
            pp3 = FMA2(W[3][k], hcv[k], pp3);
        }
        float p0 = pp0.x + pp0.y, p1 = pp1.x + pp1.y;
        float p2 = pp2.x + pp2.y, p3 = pp3.x + pp3.y;
        BF8(p0) BF8(p1) BF8(p2) BF8(p3)
        const float t01 = la ? p1 : p0;
        const float t23 = la ? p3 : p2;
        const float xv  = (lb ? t23 : t01) + xn;
        const float e = __builtin_amdgcn_exp2f(xv * negK);
        float r = __builtin_amdgcn_rcpf(1.f + e);
        r = fmaf(r, gA, gB);
        const float vi = dpp_mov<0x00>(r);
        const float vf = dpp_mov<0x55>(r);
        const float vg = dpp_mov<0xAA>(r);
        const float vo = dpp_mov<0xFF>(r);
        c = fmaf(vf, c, vi * vg);
        const float e2 = __builtin_amdgcn_exp2f(c * (-2.f * LOG2E));
        const float th = fmaf(2.f, __builtin_amdgcn_rcpf(1.f + e2), -1.f);
        const float h  = vo * th;
        const int nb = (tc + 1) & 1;
        if (l == 0) {
            h_lds[nb][20 * (g >> 4) + (g & 15)] = h;
            outp[(size_t)tc * HID] = h;
        }
        __syncthreads();
        #pragma unroll
        for (int k = 0; k < 4; ++k) {
            const v4f hv = *reinterpret_cast<const v4f*>(&h_lds[nb][20 * l + 4 * k]);
            hcv[2*k] = hv.xy; hcv[2*k+1] = hv.zw;
        }
        xn = xnn;
    }
    if (l == 0) cstate[b * HID + g] = c;
    if (t < HID) {
        const int pi = 20 * (t >> 4) + (t & 15);
        hstate[b * HID + t] = h_lds[Tc & 1][pi];
    }
}

extern "C" void kernel_launch(void* const* d_in, const int* in_sizes, int n_in,
                              void* d_out, int out_size, void* d_ws, size_t ws_size,
                              hipStream_t stream) {
    const float* x    = (const float*)d_in[0];
    const float* h0   = (const float*)d_in[1];
    const float* c0   = (const float*)d_in[2];
    const float* W_ih = (const float*)d_in[3];
    const float* W_hh = (const float*)d_in[4];
    const float* b_ih = (const float*)d_in[5];
    const float* b_hh = (const float*)d_in[6];
    float* out = (float*)d_out;

    char*  ws     = (char*)d_ws;
    float* hstate = (float*)ws;                    // 32 KB (fallback path)
    float* cstate = (float*)(ws + 32768);          // 32 KB
    int*   flags  = (int*)  (ws + 65536);          // 16 KB (64 windows x 64 b)
    float* xg     = (float*)(ws + 98304);

    const size_t xg_full = (size_t)BB * TT * G4 * sizeof(float);  // 256 MB

    if (ws_size >= 98304 + xg_full) {
        // fused producer-consumer: 64 rec blocks + 4096 xproj tile blocks
        hipMemsetAsync(flags, 0, 16384, stream);
        lstm_fused_kernel<<<dim3(BB + 4096), dim3(1024), 0, stream>>>(
            x, h0, c0, W_ih, W_hh, b_ih, b_hh, out, xg, flags);
        return;
    }

    // fallback: chunked sequential (R10)
    const size_t per_t = (size_t)BB * G4 * sizeof(float);
    size_t avail = ws_size > 98304 ? ws_size - 98304 : 0;
    long long tc_ll = (long long)(avail / per_t);
    int Tc = tc_ll > TT ? TT : (int)tc_ll;
    Tc = (Tc / 64) * 64;
    if (Tc < 64) Tc = 64;
    for (int t0 = 0; t0 < TT; t0 += Tc) {
        const int Tcur = (TT - t0 < Tc) ? (TT - t0) : Tc;
        xproj_kernel<<<dim3(4 * Tcur), dim3(512), 0, stream>>>(x, W_ih, b_ih, b_hh,
                                                               xg, t0, Tcur);
        lstm_rec_kernel<<<dim3(BB), dim3(1024), 0, stream>>>(xg, h0, c0, W_hh, out,
                                                             hstate, cstate, t0, Tcur);
    }
}